// Round 1
// baseline (825.072 us; speedup 1.0000x reference)
//
#include <hip/hip_runtime.h>
#include <hip/hip_bf16.h>

#define Sq 2048
#define Dm 2048
#define HDim 3072
#define NH 24
#define DH 128
#define FF 8192
#define ATT_SCALE 0.08838834764831845f

using bf16 = __hip_bfloat16;
typedef __attribute__((ext_vector_type(8))) short bf16x8;
typedef __attribute__((ext_vector_type(4))) float f32x4;
typedef unsigned int u32;
typedef __attribute__((ext_vector_type(4))) u32 u32x4;

// ---------------- LayerNorm + RMSNorm fused ----------------
__global__ __launch_bounds__(256) void ln_rms_kernel(
    const float* __restrict__ x, const float* __restrict__ g, const float* __restrict__ b,
    const float* __restrict__ ag, float* __restrict__ xnf, bf16* __restrict__ h)
{
    __shared__ float redA[4], redB[4], redC[4];
    int row = blockIdx.x;
    int t = threadIdx.x;
    int lane = t & 63, wid = t >> 6;
    const float* xr = x + (size_t)row * Dm;

    float v[8];
    float sum = 0.f, ssq = 0.f;
#pragma unroll
    for (int i = 0; i < 8; i++) {
        float f = xr[t + 256 * i];
        v[i] = f; sum += f; ssq += f * f;
    }
#pragma unroll
    for (int off = 32; off > 0; off >>= 1) {
        sum += __shfl_down(sum, off);
        ssq += __shfl_down(ssq, off);
    }
    if (lane == 0) { redA[wid] = sum; redB[wid] = ssq; }
    __syncthreads();
    sum = redA[0] + redA[1] + redA[2] + redA[3];
    ssq = redB[0] + redB[1] + redB[2] + redB[3];
    float mu = sum * (1.f / Dm);
    float var = ssq * (1.f / Dm) - mu * mu;
    float rstd = rsqrtf(var + 1e-5f);

    float xn[8];
    float s2 = 0.f;
#pragma unroll
    for (int i = 0; i < 8; i++) {
        int col = t + 256 * i;
        float xv = (v[i] - mu) * rstd * g[col] + b[col];
        xn[i] = xv;
        xnf[(size_t)row * Dm + col] = xv;
        s2 += xv * xv;
    }
#pragma unroll
    for (int off = 32; off > 0; off >>= 1) s2 += __shfl_down(s2, off);
    if (lane == 0) redC[wid] = s2;
    __syncthreads();
    s2 = redC[0] + redC[1] + redC[2] + redC[3];
    float rms = rsqrtf(s2 * (1.f / Dm) + 1e-5f);
#pragma unroll
    for (int i = 0; i < 8; i++) {
        int col = t + 256 * i;
        h[(size_t)row * Dm + col] = __float2bfloat16(xn[i] * rms * ag[col]);
    }
}

// ---------------- transpose + fp32->bf16 convert: W[K][N] -> Wt[N][K] ----------------
__global__ __launch_bounds__(256) void transpose_cvt_kernel(
    const float* __restrict__ W, bf16* __restrict__ Wt, int K, int N)
{
    __shared__ float tile[32][33];
    int n0 = blockIdx.x * 32, k0 = blockIdx.y * 32;
    int tx = threadIdx.x & 31, ty = threadIdx.x >> 5;  // 32 x 8
#pragma unroll
    for (int j = 0; j < 32; j += 8)
        tile[ty + j][tx] = W[(size_t)(k0 + ty + j) * N + n0 + tx];
    __syncthreads();
#pragma unroll
    for (int j = 0; j < 32; j += 8)
        Wt[(size_t)(n0 + ty + j) * K + k0 + tx] = __float2bfloat16(tile[tx][ty + j]);
}

// ---------------- bf16 MFMA GEMM: C[M][N] = A[M][K] * Bt[N][K]^T ----------------
// EPI 0: Cb = bf16(acc)
// EPI 1: o = acc + resid; Cf = o; Cb = bf16(o)    (resid/Cf may alias)
// EPI 2: o = acc + bias; Cb = bf16(gelu_tanh(o))
// EPI 3: Cf = acc + bias + resid
template <int EPI>
__global__ __launch_bounds__(256) void gemm_kernel(
    const bf16* __restrict__ A, const bf16* __restrict__ Bt,
    int M, int N, int K,
    bf16* Cb, float* Cf, const float* resid, const float* __restrict__ bias)
{
    __shared__ __align__(16) bf16 As[128][40];
    __shared__ __align__(16) bf16 Bs[128][40];
    int m0 = blockIdx.y * 128, n0 = blockIdx.x * 128;
    int tid = threadIdx.x;
    int lane = tid & 63, w = tid >> 6;
    int wr = w >> 1, wc = w & 1;
    int l15 = lane & 15, lhi = lane >> 4;

    const f32x4 zero4 = {0.f, 0.f, 0.f, 0.f};
    f32x4 acc[4][4];
#pragma unroll
    for (int m = 0; m < 4; m++)
#pragma unroll
        for (int n = 0; n < 4; n++) acc[m][n] = zero4;

    for (int k0 = 0; k0 < K; k0 += 32) {
        __syncthreads();
#pragma unroll
        for (int it = 0; it < 2; it++) {
            int c = tid + it * 256;           // 512 chunks of 8 elems
            int r = c >> 2, c8 = (c & 3) * 8;
            *reinterpret_cast<u32x4*>(&As[r][c8]) =
                *reinterpret_cast<const u32x4*>(A + (size_t)(m0 + r) * K + k0 + c8);
            *reinterpret_cast<u32x4*>(&Bs[r][c8]) =
                *reinterpret_cast<const u32x4*>(Bt + (size_t)(n0 + r) * K + k0 + c8);
        }
        __syncthreads();
        bf16x8 af[4], bfr[4];
#pragma unroll
        for (int m = 0; m < 4; m++)
            af[m] = *reinterpret_cast<const bf16x8*>(&As[wr * 64 + m * 16 + l15][lhi * 8]);
#pragma unroll
        for (int n = 0; n < 4; n++)
            bfr[n] = *reinterpret_cast<const bf16x8*>(&Bs[wc * 64 + n * 16 + l15][lhi * 8]);
#pragma unroll
        for (int m = 0; m < 4; m++)
#pragma unroll
            for (int n = 0; n < 4; n++)
                acc[m][n] = __builtin_amdgcn_mfma_f32_16x16x32_bf16(af[m], bfr[n], acc[m][n], 0, 0, 0);
    }

#pragma unroll
    for (int m = 0; m < 4; m++) {
        int row = m0 + wr * 64 + m * 16 + lhi * 4;
#pragma unroll
        for (int n = 0; n < 4; n++) {
            int col = n0 + wc * 64 + n * 16 + l15;
#pragma unroll
            for (int j = 0; j < 4; j++) {
                float vv = acc[m][n][j];
                size_t idx = (size_t)(row + j) * N + col;
                if (EPI == 0) {
                    Cb[idx] = __float2bfloat16(vv);
                } else if (EPI == 1) {
                    float o = vv + resid[idx];
                    Cf[idx] = o;
                    Cb[idx] = __float2bfloat16(o);
                } else if (EPI == 2) {
                    float o = vv + bias[col];
                    float u = 0.7978845608028654f * (o + 0.044715f * o * o * o);
                    Cb[idx] = __float2bfloat16(0.5f * o * (1.0f + tanhf(u)));
                } else {
                    Cf[idx] = vv + bias[col] + resid[idx];
                }
            }
        }
    }
}

// ---------------- flash-style causal attention ----------------
// grid: (S/64, NH); 256 threads; wave w owns q rows qb*64 + w*16 .. +15
__global__ __launch_bounds__(256) void attn_kernel(
    const bf16* __restrict__ q, const bf16* __restrict__ k, const bf16* __restrict__ v,
    bf16* __restrict__ o)
{
    __shared__ __align__(16) bf16 Ks[64][136];
    __shared__ __align__(16) bf16 Vt[128][72];
    __shared__ __align__(16) bf16 Pl[4][16][72];
    int head = blockIdx.y;
    int qb = blockIdx.x;
    int tid = threadIdx.x, lane = tid & 63, w = tid >> 6;
    int l15 = lane & 15, lhi = lane >> 4;
    int qrow0 = qb * 64 + w * 16;

    bf16x8 aq[4];
    const bf16* qbase = q + (size_t)(qrow0 + l15) * HDim + head * DH;
#pragma unroll
    for (int kk = 0; kk < 4; kk++)
        aq[kk] = *reinterpret_cast<const bf16x8*>(qbase + kk * 32 + lhi * 8);

    const f32x4 zero4 = {0.f, 0.f, 0.f, 0.f};
    f32x4 acc_o[8];
#pragma unroll
    for (int db = 0; db < 8; db++) acc_o[db] = zero4;
    float mrow[4], lrow[4];
#pragma unroll
    for (int r = 0; r < 4; r++) { mrow[r] = -1e30f; lrow[r] = 0.f; }

    for (int kb = 0; kb <= qb; kb++) {
        __syncthreads();
        // stage K tile [64][128]
#pragma unroll
        for (int it = 0; it < 4; it++) {
            int c = tid + it * 256;           // 1024 chunks of 8
            int r = c >> 4, c8 = (c & 15) * 8;
            *reinterpret_cast<u32x4*>(&Ks[r][c8]) =
                *reinterpret_cast<const u32x4*>(k + (size_t)(kb * 64 + r) * HDim + head * DH + c8);
        }
        // stage V transposed: Vt[d][kv]
#pragma unroll
        for (int i = 0; i < 32; i++) {
            int e = tid + i * 256;
            int kv = e >> 7, d = e & 127;
            Vt[d][kv] = v[(size_t)(kb * 64 + kv) * HDim + head * DH + d];
        }
        __syncthreads();

        // S = Q K^T  (16x64 per wave)
        f32x4 sacc[4];
#pragma unroll
        for (int nb = 0; nb < 4; nb++) {
            sacc[nb] = zero4;
#pragma unroll
            for (int kk = 0; kk < 4; kk++) {
                bf16x8 bk = *reinterpret_cast<const bf16x8*>(&Ks[nb * 16 + l15][kk * 32 + lhi * 8]);
                sacc[nb] = __builtin_amdgcn_mfma_f32_16x16x32_bf16(aq[kk], bk, sacc[nb], 0, 0, 0);
            }
        }

        bool diag = (kb == qb);
        float sv[4][4];
        float pm[4];
#pragma unroll
        for (int r = 0; r < 4; r++) pm[r] = -1e30f;
#pragma unroll
        for (int nb = 0; nb < 4; nb++) {
            int kvc = kb * 64 + nb * 16 + l15;
#pragma unroll
            for (int r = 0; r < 4; r++) {
                int qr = qrow0 + lhi * 4 + r;
                float s = sacc[nb][r] * ATT_SCALE;
                if (diag && kvc > qr) s = -1e30f;
                sv[nb][r] = s;
                pm[r] = fmaxf(pm[r], s);
            }
        }
#pragma unroll
        for (int off = 1; off < 16; off <<= 1)
#pragma unroll
            for (int r = 0; r < 4; r++)
                pm[r] = fmaxf(pm[r], __shfl_xor(pm[r], off));

        float ls[4];
#pragma unroll
        for (int r = 0; r < 4; r++) {
            float mnew = fmaxf(mrow[r], pm[r]);
            float sc = __expf(mrow[r] - mnew);
            mrow[r] = mnew;
            lrow[r] *= sc;
#pragma unroll
            for (int db = 0; db < 8; db++) acc_o[db][r] *= sc;
            float lsr = 0.f;
#pragma unroll
            for (int nb = 0; nb < 4; nb++) {
                float p = __expf(sv[nb][r] - mnew);
                sv[nb][r] = p;
                lsr += p;
            }
            ls[r] = lsr;
        }
#pragma unroll
        for (int off = 1; off < 16; off <<= 1)
#pragma unroll
            for (int r = 0; r < 4; r++)
                ls[r] += __shfl_xor(ls[r], off);
#pragma unroll
        for (int r = 0; r < 4; r++) lrow[r] += ls[r];

        // P -> LDS (bf16) for PV A-fragments
#pragma unroll
        for (int nb = 0; nb < 4; nb++)
#pragma unroll
            for (int r = 0; r < 4; r++)
                Pl[w][lhi * 4 + r][nb * 16 + l15] = __float2bfloat16(sv[nb][r]);

        // O += P V
#pragma unroll
        for (int ks = 0; ks < 2; ks++) {
            bf16x8 ap = *reinterpret_cast<const bf16x8*>(&Pl[w][l15][ks * 32 + lhi * 8]);
#pragma unroll
            for (int db = 0; db < 8; db++) {
                bf16x8 bv = *reinterpret_cast<const bf16x8*>(&Vt[db * 16 + l15][ks * 32 + lhi * 8]);
                acc_o[db] = __builtin_amdgcn_mfma_f32_16x16x32_bf16(ap, bv, acc_o[db], 0, 0, 0);
            }
        }
    }

#pragma unroll
    for (int db = 0; db < 8; db++)
#pragma unroll
        for (int r = 0; r < 4; r++) {
            int qr = qrow0 + lhi * 4 + r;
            float val = acc_o[db][r] / lrow[r];
            o[(size_t)qr * HDim + head * DH + db * 16 + l15] = __float2bfloat16(val);
        }
}

// ---------------- host launch ----------------
extern "C" void kernel_launch(void* const* d_in, const int* in_sizes, int n_in,
                              void* d_out, int out_size, void* d_ws, size_t ws_size,
                              hipStream_t stream)
{
    const float* x     = (const float*)d_in[0];
    const float* ln_g  = (const float*)d_in[1];
    const float* ln_b  = (const float*)d_in[2];
    const float* attng = (const float*)d_in[3];
    const float* Wq    = (const float*)d_in[4];
    const float* Wk    = (const float*)d_in[5];
    const float* Wv    = (const float*)d_in[6];
    const float* Wo    = (const float*)d_in[7];
    const float* W1    = (const float*)d_in[8];
    const float* b1    = (const float*)d_in[9];
    const float* W2    = (const float*)d_in[10];
    const float* b2    = (const float*)d_in[11];
    float* out = (float*)d_out;
    char* ws = (char*)d_ws;

    bf16*  wbuf = (bf16*)(ws + 0);                 // 33,554,432 B (max weight bf16)
    float* xnf  = (float*)(ws + 33554432);         // 16,777,216 B  (also x2f, in-place residual)
    bf16*  hbuf = (bf16*)(ws + 50331648);          //  8,388,608 B  (also x2b)
    bf16*  qb_  = (bf16*)(ws + 58720256);          // 12,582,912 B
    bf16*  kb_  = (bf16*)(ws + 71303168);          // 12,582,912 B
    bf16*  vb_  = (bf16*)(ws + 83886080);          // 12,582,912 B
    bf16*  ob_  = (bf16*)(ws + 96468992);          // 12,582,912 B  (total 109,051,904)
    bf16*  gb_  = qb_;                              // FFN hidden reuses q/k/v region
    float* x2f  = xnf;
    bf16*  x2b  = hbuf;

    ln_rms_kernel<<<Sq, 256, 0, stream>>>(x, ln_g, ln_b, attng, xnf, hbuf);

    // QKV projections
    transpose_cvt_kernel<<<dim3(HDim / 32, Dm / 32), 256, 0, stream>>>(Wq, wbuf, Dm, HDim);
    gemm_kernel<0><<<dim3(HDim / 128, Sq / 128), 256, 0, stream>>>(hbuf, wbuf, Sq, HDim, Dm, qb_, nullptr, nullptr, nullptr);
    transpose_cvt_kernel<<<dim3(HDim / 32, Dm / 32), 256, 0, stream>>>(Wk, wbuf, Dm, HDim);
    gemm_kernel<0><<<dim3(HDim / 128, Sq / 128), 256, 0, stream>>>(hbuf, wbuf, Sq, HDim, Dm, kb_, nullptr, nullptr, nullptr);
    transpose_cvt_kernel<<<dim3(HDim / 32, Dm / 32), 256, 0, stream>>>(Wv, wbuf, Dm, HDim);
    gemm_kernel<0><<<dim3(HDim / 128, Sq / 128), 256, 0, stream>>>(hbuf, wbuf, Sq, HDim, Dm, vb_, nullptr, nullptr, nullptr);

    attn_kernel<<<dim3(Sq / 64, NH), 256, 0, stream>>>(qb_, kb_, vb_, ob_);

    // out-proj + residual (dual store fp32/bf16)
    transpose_cvt_kernel<<<dim3(Dm / 32, HDim / 32), 256, 0, stream>>>(Wo, wbuf, HDim, Dm);
    gemm_kernel<1><<<dim3(Dm / 128, Sq / 128), 256, 0, stream>>>(ob_, wbuf, Sq, Dm, HDim, x2b, x2f, xnf, nullptr);

    // FFN
    transpose_cvt_kernel<<<dim3(FF / 32, Dm / 32), 256, 0, stream>>>(W1, wbuf, Dm, FF);
    gemm_kernel<2><<<dim3(FF / 128, Sq / 128), 256, 0, stream>>>(x2b, wbuf, Sq, FF, Dm, gb_, nullptr, nullptr, b1);
    transpose_cvt_kernel<<<dim3(Dm / 32, FF / 32), 256, 0, stream>>>(W2, wbuf, FF, Dm);
    gemm_kernel<3><<<dim3(Dm / 128, Sq / 128), 256, 0, stream>>>(gb_, wbuf, Sq, Dm, FF, nullptr, out, x2f, b2);
}

// Round 2
// 823.427 us; speedup vs baseline: 1.0020x; 1.0020x over previous
//
#include <hip/hip_runtime.h>
#include <hip/hip_bf16.h>

#define Sq 2048
#define Dm 2048
#define HDim 3072
#define NH 24
#define DH 128
#define FF 8192
#define ATT_SCALE 0.08838834764831845f

using bf16 = __hip_bfloat16;
typedef __attribute__((ext_vector_type(8))) short bf16x8;
typedef __attribute__((ext_vector_type(4))) float f32x4;
typedef unsigned int u32;
typedef __attribute__((ext_vector_type(4))) u32 u32x4;

// async global->LDS, 16B per lane; LDS dest = wave-uniform base + lane*16
__device__ __forceinline__ void gload_lds16(const void* g, void* l) {
    __builtin_amdgcn_global_load_lds(
        (const __attribute__((address_space(1))) void*)g,
        (__attribute__((address_space(3))) void*)l, 16, 0, 0);
}

// ---------------- LayerNorm + RMSNorm fused ----------------
__global__ __launch_bounds__(256) void ln_rms_kernel(
    const float* __restrict__ x, const float* __restrict__ g, const float* __restrict__ b,
    const float* __restrict__ ag, float* __restrict__ xnf, bf16* __restrict__ h)
{
    __shared__ float redA[4], redB[4], redC[4];
    int row = blockIdx.x;
    int t = threadIdx.x;
    int lane = t & 63, wid = t >> 6;
    const float* xr = x + (size_t)row * Dm;

    float v[8];
    float sum = 0.f, ssq = 0.f;
#pragma unroll
    for (int i = 0; i < 8; i++) {
        float f = xr[t + 256 * i];
        v[i] = f; sum += f; ssq += f * f;
    }
#pragma unroll
    for (int off = 32; off > 0; off >>= 1) {
        sum += __shfl_down(sum, off);
        ssq += __shfl_down(ssq, off);
    }
    if (lane == 0) { redA[wid] = sum; redB[wid] = ssq; }
    __syncthreads();
    sum = redA[0] + redA[1] + redA[2] + redA[3];
    ssq = redB[0] + redB[1] + redB[2] + redB[3];
    float mu = sum * (1.f / Dm);
    float var = ssq * (1.f / Dm) - mu * mu;
    float rstd = rsqrtf(var + 1e-5f);

    float xn[8];
    float s2 = 0.f;
#pragma unroll
    for (int i = 0; i < 8; i++) {
        int col = t + 256 * i;
        float xv = (v[i] - mu) * rstd * g[col] + b[col];
        xn[i] = xv;
        xnf[(size_t)row * Dm + col] = xv;
        s2 += xv * xv;
    }
#pragma unroll
    for (int off = 32; off > 0; off >>= 1) s2 += __shfl_down(s2, off);
    if (lane == 0) redC[wid] = s2;
    __syncthreads();
    s2 = redC[0] + redC[1] + redC[2] + redC[3];
    float rms = rsqrtf(s2 * (1.f / Dm) + 1e-5f);
#pragma unroll
    for (int i = 0; i < 8; i++) {
        int col = t + 256 * i;
        h[(size_t)row * Dm + col] = __float2bfloat16(xn[i] * rms * ag[col]);
    }
}

// ---------------- transpose + fp32->bf16 convert: W[K][N] -> Wt[N][K] ----------------
__global__ __launch_bounds__(256) void transpose_cvt_kernel(
    const float* __restrict__ W, bf16* __restrict__ Wt, int K, int N)
{
    __shared__ float tile[32][33];
    int n0 = blockIdx.x * 32, k0 = blockIdx.y * 32;
    int tx = threadIdx.x & 31, ty = threadIdx.x >> 5;  // 32 x 8
#pragma unroll
    for (int j = 0; j < 32; j += 8)
        tile[ty + j][tx] = W[(size_t)(k0 + ty + j) * N + n0 + tx];
    __syncthreads();
#pragma unroll
    for (int j = 0; j < 32; j += 8)
        Wt[(size_t)(n0 + ty + j) * K + k0 + tx] = __float2bfloat16(tile[tx][ty + j]);
}

// ---------------- bf16 MFMA GEMM (m97 structure): C = A * Bt^T ----------------
template <int EPI>
__global__ __launch_bounds__(256) void gemm_kernel(
    const bf16* __restrict__ A, const bf16* __restrict__ Bt,
    int M, int N, int K,
    bf16* Cb, float* Cf, const float* resid, const float* __restrict__ bias)
{
    __shared__ __align__(16) bf16 As[128 * 32];
    __shared__ __align__(16) bf16 Bs[128 * 32];
    int m0 = blockIdx.y * 128, n0 = blockIdx.x * 128;
    int tid = threadIdx.x;
    int lane = tid & 63, w = tid >> 6;
    int wr = w >> 1, wc = w & 1;
    int l15 = lane & 15, lhi = lane >> 4;
    int srow = lane >> 2;            // 0..15
    int skel = (lane & 3) * 8;       // k elem offset

    const f32x4 zero4 = {0.f, 0.f, 0.f, 0.f};
    f32x4 acc[4][4];
#pragma unroll
    for (int m = 0; m < 4; m++)
#pragma unroll
        for (int n = 0; n < 4; n++) acc[m][n] = zero4;

    for (int k0 = 0; k0 < K; k0 += 32) {
        __syncthreads();
#pragma unroll
        for (int c = 0; c < 2; c++) {
            int row = w * 32 + c * 16 + srow;
            gload_lds16(A + (size_t)(m0 + row) * K + k0 + skel,
                        (char*)As + w * 2048 + c * 1024);
            gload_lds16(Bt + (size_t)(n0 + row) * K + k0 + skel,
                        (char*)Bs + w * 2048 + c * 1024);
        }
        __syncthreads();
        bf16x8 af[4], bfr[4];
#pragma unroll
        for (int m = 0; m < 4; m++)
            af[m] = *reinterpret_cast<const bf16x8*>(&As[(wr * 64 + m * 16 + l15) * 32 + lhi * 8]);
#pragma unroll
        for (int n = 0; n < 4; n++)
            bfr[n] = *reinterpret_cast<const bf16x8*>(&Bs[(wc * 64 + n * 16 + l15) * 32 + lhi * 8]);
#pragma unroll
        for (int m = 0; m < 4; m++)
#pragma unroll
            for (int n = 0; n < 4; n++)
                acc[m][n] = __builtin_amdgcn_mfma_f32_16x16x32_bf16(af[m], bfr[n], acc[m][n], 0, 0, 0);
    }

#pragma unroll
    for (int m = 0; m < 4; m++) {
        int row = m0 + wr * 64 + m * 16 + lhi * 4;
#pragma unroll
        for (int n = 0; n < 4; n++) {
            int col = n0 + wc * 64 + n * 16 + l15;
#pragma unroll
            for (int j = 0; j < 4; j++) {
                float vv = acc[m][n][j];
                size_t idx = (size_t)(row + j) * N + col;
                if (EPI == 0) {
                    Cb[idx] = __float2bfloat16(vv);
                } else if (EPI == 1) {
                    float o = vv + resid[idx];
                    Cf[idx] = o;
                    Cb[idx] = __float2bfloat16(o);
                } else if (EPI == 2) {
                    float o = vv + bias[col];
                    float u = 0.7978845608028654f * (o + 0.044715f * o * o * o);
                    Cb[idx] = __float2bfloat16(0.5f * o * (1.0f + tanhf(u)));
                } else {
                    Cf[idx] = vv + bias[col] + resid[idx];
                }
            }
        }
    }
}

// ---------------- flash-style causal attention ----------------
__global__ __launch_bounds__(256) void attn_kernel(
    const bf16* __restrict__ q, const bf16* __restrict__ k, const bf16* __restrict__ v,
    bf16* __restrict__ o)
{
    __shared__ __align__(16) bf16 KsF[64 * 128];   // swizzled: slot s of row r holds block s^(r&7)
    __shared__ __align__(16) bf16 VtF[128 * 72];   // V^T with kv-block XOR swizzle
    __shared__ __align__(16) bf16 Pl[4][16][72];
    int head = blockIdx.y;
    int qb = blockIdx.x;
    int tid = threadIdx.x, lane = tid & 63, w = tid >> 6;
    int l15 = lane & 15, lhi = lane >> 4;
    int qrow0 = qb * 64 + w * 16;

    bf16x8 aq[4];
    const bf16* qbase = q + (size_t)(qrow0 + l15) * HDim + head * DH;
#pragma unroll
    for (int kk = 0; kk < 4; kk++)
        aq[kk] = *reinterpret_cast<const bf16x8*>(qbase + kk * 32 + lhi * 8);

    const f32x4 zero4 = {0.f, 0.f, 0.f, 0.f};
    f32x4 acc_o[8];
#pragma unroll
    for (int db = 0; db < 8; db++) acc_o[db] = zero4;
    float mrow[4], lrow[4];
#pragma unroll
    for (int r = 0; r < 4; r++) { mrow[r] = -1e30f; lrow[r] = 0.f; }

    for (int kb = 0; kb <= qb; kb++) {
        int kv0 = kb * 64;
        __syncthreads();
        // stage K tile via global_load_lds (source pre-swizzled for block XOR)
#pragma unroll
        for (int c = 0; c < 4; c++) {
            int row = w * 16 + c * 4 + lhi;
            int cb = l15 ^ (row & 7);
            gload_lds16(k + (size_t)(kv0 + row) * HDim + head * DH + cb * 8,
                        (char*)KsF + w * 4096 + c * 1024);
        }
        // stage V transposed: vectorized global reads, swizzled scalar LDS writes
#pragma unroll
        for (int i = 0; i < 4; i++) {
            int kv = (tid >> 4) + i * 16;
            int d0 = (tid & 15) * 8;
            bf16x8 vv = *reinterpret_cast<const bf16x8*>(
                v + (size_t)(kv0 + kv) * HDim + head * DH + d0);
            int vb = kv >> 3, kr = kv & 7;
            int xr = (d0 >> 3) & 7;
#pragma unroll
            for (int j = 0; j < 8; j++) {
                int d = d0 + j;
                VtF[d * 72 + ((vb ^ xr) << 3) + kr] = ((const bf16*)&vv)[j];
            }
        }
        __syncthreads();

        // S = Q K^T  (16x64 per wave)
        f32x4 sacc[4];
#pragma unroll
        for (int nb = 0; nb < 4; nb++) {
            sacc[nb] = zero4;
            int krow = nb * 16 + l15;
#pragma unroll
            for (int kk = 0; kk < 4; kk++) {
                const char* kp = (const char*)KsF + krow * 256 +
                                 ((kk * 64 + lhi * 16) ^ ((krow & 7) << 4));
                bf16x8 bk = *reinterpret_cast<const bf16x8*>(kp);
                sacc[nb] = __builtin_amdgcn_mfma_f32_16x16x32_bf16(aq[kk], bk, sacc[nb], 0, 0, 0);
            }
        }

        bool diag = (kb == qb);
        float sv[4][4];
        float pm[4];
#pragma unroll
        for (int r = 0; r < 4; r++) pm[r] = -1e30f;
#pragma unroll
        for (int nb = 0; nb < 4; nb++) {
            int kvc = kv0 + nb * 16 + l15;
#pragma unroll
            for (int r = 0; r < 4; r++) {
                int qr = qrow0 + lhi * 4 + r;
                float s = sacc[nb][r] * ATT_SCALE;
                if (diag && kvc > qr) s = -1e30f;
                sv[nb][r] = s;
                pm[r] = fmaxf(pm[r], s);
            }
        }
#pragma unroll
        for (int off = 1; off < 16; off <<= 1)
#pragma unroll
            for (int r = 0; r < 4; r++)
                pm[r] = fmaxf(pm[r], __shfl_xor(pm[r], off));

        float ls[4];
#pragma unroll
        for (int r = 0; r < 4; r++) {
            float mnew = fmaxf(mrow[r], pm[r]);
            float sc = __expf(mrow[r] - mnew);
            mrow[r] = mnew;
            lrow[r] *= sc;
#pragma unroll
            for (int db = 0; db < 8; db++) acc_o[db][r] *= sc;
            float lsr = 0.f;
#pragma unroll
            for (int nb = 0; nb < 4; nb++) {
                float p = __expf(sv[nb][r] - mnew);
                sv[nb][r] = p;
                lsr += p;
            }
            ls[r] = lsr;
        }
#pragma unroll
        for (int off = 1; off < 16; off <<= 1)
#pragma unroll
            for (int r = 0; r < 4; r++)
                ls[r] += __shfl_xor(ls[r], off);
#pragma unroll
        for (int r = 0; r < 4; r++) lrow[r] += ls[r];

        // P -> LDS (bf16) for PV A-fragments
#pragma unroll
        for (int nb = 0; nb < 4; nb++)
#pragma unroll
            for (int r = 0; r < 4; r++)
                Pl[w][lhi * 4 + r][nb * 16 + l15] = __float2bfloat16(sv[nb][r]);

        // O += P V
#pragma unroll
        for (int ks = 0; ks < 2; ks++) {
            bf16x8 ap = *reinterpret_cast<const bf16x8*>(&Pl[w][l15][ks * 32 + lhi * 8]);
#pragma unroll
            for (int db = 0; db < 8; db++) {
                int dv = db * 16 + l15;
                int blk = (ks * 4 + lhi) ^ ((dv >> 3) & 7);
                bf16x8 bv = *reinterpret_cast<const bf16x8*>(&VtF[dv * 72 + blk * 8]);
                acc_o[db] = __builtin_amdgcn_mfma_f32_16x16x32_bf16(ap, bv, acc_o[db], 0, 0, 0);
            }
        }
    }

#pragma unroll
    for (int db = 0; db < 8; db++)
#pragma unroll
        for (int r = 0; r < 4; r++) {
            int qr = qrow0 + lhi * 4 + r;
            float val = acc_o[db][r] / lrow[r];
            o[(size_t)qr * HDim + head * DH + db * 16 + l15] = __float2bfloat16(val);
        }
}

// ---------------- host launch ----------------
extern "C" void kernel_launch(void* const* d_in, const int* in_sizes, int n_in,
                              void* d_out, int out_size, void* d_ws, size_t ws_size,
                              hipStream_t stream)
{
    const float* x     = (const float*)d_in[0];
    const float* ln_g  = (const float*)d_in[1];
    const float* ln_b  = (const float*)d_in[2];
    const float* attng = (const float*)d_in[3];
    const float* Wq    = (const float*)d_in[4];
    const float* Wk    = (const float*)d_in[5];
    const float* Wv    = (const float*)d_in[6];
    const float* Wo    = (const float*)d_in[7];
    const float* W1    = (const float*)d_in[8];
    const float* b1    = (const float*)d_in[9];
    const float* W2    = (const float*)d_in[10];
    const float* b2    = (const float*)d_in[11];
    float* out = (float*)d_out;
    char* ws = (char*)d_ws;

    bf16*  wbuf = (bf16*)(ws + 0);
    float* xnf  = (float*)(ws + 33554432);
    bf16*  hbuf = (bf16*)(ws + 50331648);
    bf16*  qb_  = (bf16*)(ws + 58720256);
    bf16*  kb_  = (bf16*)(ws + 71303168);
    bf16*  vb_  = (bf16*)(ws + 83886080);
    bf16*  ob_  = (bf16*)(ws + 96468992);
    bf16*  gb_  = qb_;
    float* x2f  = xnf;
    bf16*  x2b  = hbuf;

    ln_rms_kernel<<<Sq, 256, 0, stream>>>(x, ln_g, ln_b, attng, xnf, hbuf);

    transpose_cvt_kernel<<<dim3(HDim / 32, Dm / 32), 256, 0, stream>>>(Wq, wbuf, Dm, HDim);
    gemm_kernel<0><<<dim3(HDim / 128, Sq / 128), 256, 0, stream>>>(hbuf, wbuf, Sq, HDim, Dm, qb_, nullptr, nullptr, nullptr);
    transpose_cvt_kernel<<<dim3(HDim / 32, Dm / 32), 256, 0, stream>>>(Wk, wbuf, Dm, HDim);
    gemm_kernel<0><<<dim3(HDim / 128, Sq / 128), 256, 0, stream>>>(hbuf, wbuf, Sq, HDim, Dm, kb_, nullptr, nullptr, nullptr);
    transpose_cvt_kernel<<<dim3(HDim / 32, Dm / 32), 256, 0, stream>>>(Wv, wbuf, Dm, HDim);
    gemm_kernel<0><<<dim3(HDim / 128, Sq / 128), 256, 0, stream>>>(hbuf, wbuf, Sq, HDim, Dm, vb_, nullptr, nullptr, nullptr);

    attn_kernel<<<dim3(Sq / 64, NH), 256, 0, stream>>>(qb_, kb_, vb_, ob_);

    transpose_cvt_kernel<<<dim3(Dm / 32, HDim / 32), 256, 0, stream>>>(Wo, wbuf, HDim, Dm);
    gemm_kernel<1><<<dim3(Dm / 128, Sq / 128), 256, 0, stream>>>(ob_, wbuf, Sq, Dm, HDim, x2b, x2f, xnf, nullptr);

    transpose_cvt_kernel<<<dim3(FF / 32, Dm / 32), 256, 0, stream>>>(W1, wbuf, Dm, FF);
    gemm_kernel<2><<<dim3(FF / 128, Sq / 128), 256, 0, stream>>>(x2b, wbuf, Sq, FF, Dm, gb_, nullptr, nullptr, b1);
    transpose_cvt_kernel<<<dim3(Dm / 32, FF / 32), 256, 0, stream>>>(W2, wbuf, FF, Dm);
    gemm_kernel<3><<<dim3(Dm / 128, Sq / 128), 256, 0, stream>>>(gb_, wbuf, Sq, Dm, FF, nullptr, out, x2f, b2);
}

// Round 3
// 591.285 us; speedup vs baseline: 1.3954x; 1.3926x over previous
//
#include <hip/hip_runtime.h>
#include <hip/hip_bf16.h>

#define Sq 2048
#define Dm 2048
#define HDim 3072
#define QKVDim 9216
#define NH 24
#define DH 128
#define FF 8192
#define ATT_SCALE 0.08838834764831845f

using bf16 = __hip_bfloat16;
typedef __attribute__((ext_vector_type(8))) short bf16x8;
typedef __attribute__((ext_vector_type(4))) float f32x4;
typedef unsigned int u32;
typedef __attribute__((ext_vector_type(4))) u32 u32x4;

// async global->LDS, 16B per lane; LDS dest = wave-uniform base + lane*16
__device__ __forceinline__ void gload_lds16(const void* g, void* l) {
    __builtin_amdgcn_global_load_lds(
        (const __attribute__((address_space(1))) void*)g,
        (__attribute__((address_space(3))) void*)l, 16, 0, 0);
}

// ---------------- LayerNorm + RMSNorm fused ----------------
__global__ __launch_bounds__(256) void ln_rms_kernel(
    const float* __restrict__ x, const float* __restrict__ g, const float* __restrict__ b,
    const float* __restrict__ ag, float* __restrict__ xnf, bf16* __restrict__ h)
{
    __shared__ float redA[4], redB[4], redC[4];
    int row = blockIdx.x;
    int t = threadIdx.x;
    int lane = t & 63, wid = t >> 6;
    const float* xr = x + (size_t)row * Dm;

    float v[8];
    float sum = 0.f, ssq = 0.f;
#pragma unroll
    for (int i = 0; i < 8; i++) {
        float f = xr[t + 256 * i];
        v[i] = f; sum += f; ssq += f * f;
    }
#pragma unroll
    for (int off = 32; off > 0; off >>= 1) {
        sum += __shfl_down(sum, off);
        ssq += __shfl_down(ssq, off);
    }
    if (lane == 0) { redA[wid] = sum; redB[wid] = ssq; }
    __syncthreads();
    sum = redA[0] + redA[1] + redA[2] + redA[3];
    ssq = redB[0] + redB[1] + redB[2] + redB[3];
    float mu = sum * (1.f / Dm);
    float var = ssq * (1.f / Dm) - mu * mu;
    float rstd = rsqrtf(var + 1e-5f);

    float xn[8];
    float s2 = 0.f;
#pragma unroll
    for (int i = 0; i < 8; i++) {
        int col = t + 256 * i;
        float xv = (v[i] - mu) * rstd * g[col] + b[col];
        xn[i] = xv;
        xnf[(size_t)row * Dm + col] = xv;
        s2 += xv * xv;
    }
#pragma unroll
    for (int off = 32; off > 0; off >>= 1) s2 += __shfl_down(s2, off);
    if (lane == 0) redC[wid] = s2;
    __syncthreads();
    s2 = redC[0] + redC[1] + redC[2] + redC[3];
    float rms = rsqrtf(s2 * (1.f / Dm) + 1e-5f);
#pragma unroll
    for (int i = 0; i < 8; i++) {
        int col = t + 256 * i;
        h[(size_t)row * Dm + col] = __float2bfloat16(xn[i] * rms * ag[col]);
    }
}

// ---------------- transpose + fp32->bf16 convert: W[K][N] -> Wt[N][K] ----------------
__global__ __launch_bounds__(256) void transpose_cvt_kernel(
    const float* __restrict__ W, bf16* __restrict__ Wt, int K, int N)
{
    __shared__ float tile[32][33];
    int n0 = blockIdx.x * 32, k0 = blockIdx.y * 32;
    int tx = threadIdx.x & 31, ty = threadIdx.x >> 5;  // 32 x 8
#pragma unroll
    for (int j = 0; j < 32; j += 8)
        tile[ty + j][tx] = W[(size_t)(k0 + ty + j) * N + n0 + tx];
    __syncthreads();
#pragma unroll
    for (int j = 0; j < 32; j += 8)
        Wt[(size_t)(n0 + ty + j) * K + k0 + tx] = __float2bfloat16(tile[tx][ty + j]);
}

// ---------------- fp32 -> bf16 convert ----------------
__global__ __launch_bounds__(256) void cvt_bf16_kernel(
    const float* __restrict__ in, bf16* __restrict__ o, int n)
{
    int i = (blockIdx.x * 256 + threadIdx.x) * 8;
    if (i >= n) return;
    f32x4 a = *reinterpret_cast<const f32x4*>(in + i);
    f32x4 b = *reinterpret_cast<const f32x4*>(in + i + 4);
    bf16 r[8];
#pragma unroll
    for (int j = 0; j < 4; j++) { r[j] = __float2bfloat16(a[j]); r[4 + j] = __float2bfloat16(b[j]); }
    *reinterpret_cast<u32x4*>(o + i) = *reinterpret_cast<u32x4*>(r);
}

// ---------------- prefill: out[row][col] = resid[row][col] + bias[col] ----------------
__global__ __launch_bounds__(256) void prefill_kernel(
    const float* __restrict__ resid, const float* __restrict__ bias,
    float* __restrict__ o, int N)
{
    int i = (blockIdx.x * 256 + threadIdx.x) * 4;
    int col = i % N;
    f32x4 r = *reinterpret_cast<const f32x4*>(resid + i);
    f32x4 b = *reinterpret_cast<const f32x4*>(bias + col);
    f32x4 ov = {r[0] + b[0], r[1] + b[1], r[2] + b[2], r[3] + b[3]};
    *reinterpret_cast<f32x4*>(o + i) = ov;
}

// ---------------- bf16 MFMA GEMM (m97 structure): C = A * Bt^T ----------------
// EPI 0: Cb = bf16(acc)
// EPI 2: o = acc + bias; Cb = bf16(gelu_tanh(o))
// EPI 4: atomicAdd(Cf[idx], acc)            (split-K partial)
template <int EPI>
__global__ __launch_bounds__(256) void gemm_kernel(
    const bf16* __restrict__ A, const bf16* __restrict__ Bt,
    int M, int N, int K, int Ksplit,
    bf16* Cb, float* Cf, const float* __restrict__ bias)
{
    __shared__ __align__(16) bf16 As[128 * 32];
    __shared__ __align__(16) bf16 Bs[128 * 32];
    int m0 = blockIdx.y * 128, n0 = blockIdx.x * 128;
    int kbeg = blockIdx.z * Ksplit, kend = kbeg + Ksplit;
    int tid = threadIdx.x;
    int lane = tid & 63, w = tid >> 6;
    int wr = w >> 1, wc = w & 1;
    int l15 = lane & 15, lhi = lane >> 4;
    int srow = lane >> 2;            // 0..15
    int skel = (lane & 3) * 8;       // k elem offset

    const f32x4 zero4 = {0.f, 0.f, 0.f, 0.f};
    f32x4 acc[4][4];
#pragma unroll
    for (int m = 0; m < 4; m++)
#pragma unroll
        for (int n = 0; n < 4; n++) acc[m][n] = zero4;

    for (int k0 = kbeg; k0 < kend; k0 += 32) {
        __syncthreads();
#pragma unroll
        for (int c = 0; c < 2; c++) {
            int row = w * 32 + c * 16 + srow;
            gload_lds16(A + (size_t)(m0 + row) * K + k0 + skel,
                        (char*)As + w * 2048 + c * 1024);
            gload_lds16(Bt + (size_t)(n0 + row) * K + k0 + skel,
                        (char*)Bs + w * 2048 + c * 1024);
        }
        __syncthreads();
        bf16x8 af[4], bfr[4];
#pragma unroll
        for (int m = 0; m < 4; m++)
            af[m] = *reinterpret_cast<const bf16x8*>(&As[(wr * 64 + m * 16 + l15) * 32 + lhi * 8]);
#pragma unroll
        for (int n = 0; n < 4; n++)
            bfr[n] = *reinterpret_cast<const bf16x8*>(&Bs[(wc * 64 + n * 16 + l15) * 32 + lhi * 8]);
#pragma unroll
        for (int m = 0; m < 4; m++)
#pragma unroll
            for (int n = 0; n < 4; n++)
                acc[m][n] = __builtin_amdgcn_mfma_f32_16x16x32_bf16(af[m], bfr[n], acc[m][n], 0, 0, 0);
    }

#pragma unroll
    for (int m = 0; m < 4; m++) {
        int row = m0 + wr * 64 + m * 16 + lhi * 4;
#pragma unroll
        for (int n = 0; n < 4; n++) {
            int col = n0 + wc * 64 + n * 16 + l15;
#pragma unroll
            for (int j = 0; j < 4; j++) {
                float vv = acc[m][n][j];
                size_t idx = (size_t)(row + j) * N + col;
                if (EPI == 0) {
                    Cb[idx] = __float2bfloat16(vv);
                } else if (EPI == 2) {
                    float o = vv + bias[col];
                    float u = 0.7978845608028654f * (o + 0.044715f * o * o * o);
                    Cb[idx] = __float2bfloat16(0.5f * o * (1.0f + tanhf(u)));
                } else {
                    atomicAdd(&Cf[idx], vv);
                }
            }
        }
    }
}

// ---------------- flash-style causal attention ----------------
// 1D grid of NH * (Sq/64) blocks, work-descending: heaviest q-tiles first.
// q/k/v are slices of the fused qkv buffer, row stride QKVDim.
__global__ __launch_bounds__(256) void attn_kernel(
    const bf16* __restrict__ qkv, bf16* __restrict__ o)
{
    __shared__ __align__(16) bf16 KsF[64 * 128];   // swizzled: slot s of row r holds block s^(r&7)
    __shared__ __align__(16) bf16 VtF[128 * 72];   // V^T with kv-block XOR swizzle
    __shared__ __align__(16) bf16 Pl[4][16][72];
    int rank = blockIdx.x;
    int qb = (Sq / 64 - 1) - rank / NH;    // heaviest first
    int head = rank % NH;
    const bf16* q = qkv + head * DH;
    const bf16* k = qkv + HDim + head * DH;
    const bf16* v = qkv + 2 * HDim + head * DH;
    int tid = threadIdx.x, lane = tid & 63, w = tid >> 6;
    int l15 = lane & 15, lhi = lane >> 4;
    int qrow0 = qb * 64 + w * 16;

    bf16x8 aq[4];
    const bf16* qbase = q + (size_t)(qrow0 + l15) * QKVDim;
#pragma unroll
    for (int kk = 0; kk < 4; kk++)
        aq[kk] = *reinterpret_cast<const bf16x8*>(qbase + kk * 32 + lhi * 8);

    const f32x4 zero4 = {0.f, 0.f, 0.f, 0.f};
    f32x4 acc_o[8];
#pragma unroll
    for (int db = 0; db < 8; db++) acc_o[db] = zero4;
    float mrow[4], lrow[4];
#pragma unroll
    for (int r = 0; r < 4; r++) { mrow[r] = -1e30f; lrow[r] = 0.f; }

    for (int kb = 0; kb <= qb; kb++) {
        int kv0 = kb * 64;
        __syncthreads();
        // stage K tile via global_load_lds (source pre-swizzled for block XOR)
#pragma unroll
        for (int c = 0; c < 4; c++) {
            int row = w * 16 + c * 4 + lhi;
            int cb = l15 ^ (row & 7);
            gload_lds16(k + (size_t)(kv0 + row) * QKVDim + cb * 8,
                        (char*)KsF + w * 4096 + c * 1024);
        }
        // stage V transposed: vectorized global reads, swizzled scalar LDS writes
#pragma unroll
        for (int i = 0; i < 4; i++) {
            int kv = (tid >> 4) + i * 16;
            int d0 = (tid & 15) * 8;
            bf16x8 vv = *reinterpret_cast<const bf16x8*>(
                v + (size_t)(kv0 + kv) * QKVDim + d0);
            int vb = kv >> 3, kr = kv & 7;
            int xr = (d0 >> 3) & 7;
#pragma unroll
            for (int j = 0; j < 8; j++) {
                int d = d0 + j;
                VtF[d * 72 + ((vb ^ xr) << 3) + kr] = ((const bf16*)&vv)[j];
            }
        }
        __syncthreads();

        // S = Q K^T  (16x64 per wave)
        f32x4 sacc[4];
#pragma unroll
        for (int nb = 0; nb < 4; nb++) {
            sacc[nb] = zero4;
            int krow = nb * 16 + l15;
#pragma unroll
            for (int kk = 0; kk < 4; kk++) {
                const char* kp = (const char*)KsF + krow * 256 +
                                 ((kk * 64 + lhi * 16) ^ ((krow & 7) << 4));
                bf16x8 bk = *reinterpret_cast<const bf16x8*>(kp);
                sacc[nb] = __builtin_amdgcn_mfma_f32_16x16x32_bf16(aq[kk], bk, sacc[nb], 0, 0, 0);
            }
        }

        bool diag = (kb == qb);
        float sv[4][4];
        float pm[4];
#pragma unroll
        for (int r = 0; r < 4; r++) pm[r] = -1e30f;
#pragma unroll
        for (int nb = 0; nb < 4; nb++) {
            int kvc = kv0 + nb * 16 + l15;
#pragma unroll
            for (int r = 0; r < 4; r++) {
                int qr = qrow0 + lhi * 4 + r;
                float s = sacc[nb][r] * ATT_SCALE;
                if (diag && kvc > qr) s = -1e30f;
                sv[nb][r] = s;
                pm[r] = fmaxf(pm[r], s);
            }
        }
#pragma unroll
        for (int off = 1; off < 16; off <<= 1)
#pragma unroll
            for (int r = 0; r < 4; r++)
                pm[r] = fmaxf(pm[r], __shfl_xor(pm[r], off));

        float ls[4];
#pragma unroll
        for (int r = 0; r < 4; r++) {
            float mnew = fmaxf(mrow[r], pm[r]);
            float sc = __expf(mrow[r] - mnew);
            mrow[r] = mnew;
            lrow[r] *= sc;
#pragma unroll
            for (int db = 0; db < 8; db++) acc_o[db][r] *= sc;
            float lsr = 0.f;
#pragma unroll
            for (int nb = 0; nb < 4; nb++) {
                float p = __expf(sv[nb][r] - mnew);
                sv[nb][r] = p;
                lsr += p;
            }
            ls[r] = lsr;
        }
#pragma unroll
        for (int off = 1; off < 16; off <<= 1)
#pragma unroll
            for (int r = 0; r < 4; r++)
                ls[r] += __shfl_xor(ls[r], off);
#pragma unroll
        for (int r = 0; r < 4; r++) lrow[r] += ls[r];

        // P -> LDS (bf16) for PV A-fragments
#pragma unroll
        for (int nb = 0; nb < 4; nb++)
#pragma unroll
            for (int r = 0; r < 4; r++)
                Pl[w][lhi * 4 + r][nb * 16 + l15] = __float2bfloat16(sv[nb][r]);

        // O += P V
#pragma unroll
        for (int ks = 0; ks < 2; ks++) {
            bf16x8 ap = *reinterpret_cast<const bf16x8*>(&Pl[w][l15][ks * 32 + lhi * 8]);
#pragma unroll
            for (int db = 0; db < 8; db++) {
                int dv = db * 16 + l15;
                int blk = (ks * 4 + lhi) ^ ((dv >> 3) & 7);
                bf16x8 bv = *reinterpret_cast<const bf16x8*>(&VtF[dv * 72 + blk * 8]);
                acc_o[db] = __builtin_amdgcn_mfma_f32_16x16x32_bf16(ap, bv, acc_o[db], 0, 0, 0);
            }
        }
    }

#pragma unroll
    for (int db = 0; db < 8; db++)
#pragma unroll
        for (int r = 0; r < 4; r++) {
            int qr = qrow0 + lhi * 4 + r;
            float val = acc_o[db][r] / lrow[r];
            o[(size_t)qr * HDim + head * DH + db * 16 + l15] = __float2bfloat16(val);
        }
}

// ---------------- host launch ----------------
extern "C" void kernel_launch(void* const* d_in, const int* in_sizes, int n_in,
                              void* d_out, int out_size, void* d_ws, size_t ws_size,
                              hipStream_t stream)
{
    const float* x     = (const float*)d_in[0];
    const float* ln_g  = (const float*)d_in[1];
    const float* ln_b  = (const float*)d_in[2];
    const float* attng = (const float*)d_in[3];
    const float* Wq    = (const float*)d_in[4];
    const float* Wk    = (const float*)d_in[5];
    const float* Wv    = (const float*)d_in[6];
    const float* Wo    = (const float*)d_in[7];
    const float* W1    = (const float*)d_in[8];
    const float* b1    = (const float*)d_in[9];
    const float* W2    = (const float*)d_in[10];
    const float* b2    = (const float*)d_in[11];
    float* out = (float*)d_out;
    char* ws = (char*)d_ws;

    // ws layout (110 MB):
    bf16*  wbuf = (bf16*)(ws + 0);           // 38 MB: transposed weights (max QKV 9216x2048 bf16 = 36MB)
    float* xnf  = (float*)(ws + 39845888);   // 16 MB: LN output fp32; becomes x2 after Wo atomic accum
    bf16*  hbuf = (bf16*)(ws + 56623104);    //  8 MB: rmsnorm bf16; later x2 bf16
    bf16*  qkv  = (bf16*)(ws + 65011712);    // 36 MB: fused q|k|v [2048][9216]; later FFN hidden [2048][8192]
    bf16*  ob_  = (bf16*)(ws + 102760448);   // 12 MB: attention output [2048][3072]   (total 114.75 MB)
    bf16*  gb_  = qkv;

    // 1) outer LN + attention prenorm RMSNorm
    ln_rms_kernel<<<Sq, 256, 0, stream>>>(x, ln_g, ln_b, attng, xnf, hbuf);

    // 2) fused QKV projection: Wt rows [0,3072)=Wq^T, [3072,6144)=Wk^T, [6144,9216)=Wv^T
    transpose_cvt_kernel<<<dim3(HDim / 32, Dm / 32), 256, 0, stream>>>(Wq, wbuf, Dm, HDim);
    transpose_cvt_kernel<<<dim3(HDim / 32, Dm / 32), 256, 0, stream>>>(Wk, wbuf + (size_t)HDim * Dm, Dm, HDim);
    transpose_cvt_kernel<<<dim3(HDim / 32, Dm / 32), 256, 0, stream>>>(Wv, wbuf + (size_t)2 * HDim * Dm, Dm, HDim);
    gemm_kernel<0><<<dim3(QKVDim / 128, Sq / 128, 1), 256, 0, stream>>>(
        hbuf, wbuf, Sq, QKVDim, Dm, Dm, qkv, nullptr, nullptr);

    // 3) attention (work-descending 1D grid)
    attn_kernel<<<dim3(NH * Sq / 64), 256, 0, stream>>>(qkv, ob_);

    // 4) out-proj, split-K=2, atomic-accumulate into xnf (xnf already holds the residual)
    transpose_cvt_kernel<<<dim3(Dm / 32, HDim / 32), 256, 0, stream>>>(Wo, wbuf, HDim, Dm);
    gemm_kernel<4><<<dim3(Dm / 128, Sq / 128, 2), 256, 0, stream>>>(
        ob_, wbuf, Sq, Dm, HDim, HDim / 2, nullptr, xnf, nullptr);
    // x2 bf16 for FFN1 input
    cvt_bf16_kernel<<<(Sq * Dm) / (256 * 8), 256, 0, stream>>>(xnf, hbuf, Sq * Dm);

    // 5) FFN1 (+bias +gelu) -> gb (reuses qkv region)
    transpose_cvt_kernel<<<dim3(FF / 32, Dm / 32), 256, 0, stream>>>(W1, wbuf, Dm, FF);
    gemm_kernel<2><<<dim3(FF / 128, Sq / 128, 1), 256, 0, stream>>>(
        hbuf, wbuf, Sq, FF, Dm, Dm, gb_, nullptr, b1);

    // 6) FFN2: prefill out = x2 + b2, then split-K=2 atomic accumulate
    transpose_cvt_kernel<<<dim3(Dm / 32, FF / 32), 256, 0, stream>>>(W2, wbuf, FF, Dm);
    prefill_kernel<<<(Sq * Dm) / (256 * 4), 256, 0, stream>>>(xnf, b2, out, Dm);
    gemm_kernel<4><<<dim3(Dm / 128, Sq / 128, 2), 256, 0, stream>>>(
        gb_, wbuf, Sq, Dm, FF, FF / 2, nullptr, out, nullptr);
}